// Round 3
// baseline (563.088 us; speedup 1.0000x reference)
//
#include <hip/hip_runtime.h>
#include <cmath>

// AttentionBlock fused pipeline for MI355X (gfx950). Dtype-adaptive:
// a probe kernel detects whether inputs are fp32 or bf16; compute pipeline
// runs in bf16 MFMA either way; epilogue/residual/output honor the real dtype.
//
// B=4, C=256, N=32768, G=4 (64ch/group), NH=8, hd=32.
// Pipeline per batch-pass of nb batches:
//   xt[b][n][c] = (gn_w[c]*rstd[b,g]) * xw[b][c][n]     (transpose+scale, bf16)
//   qkv = qkv_w @ xt^T + beta_b     -> q: qT[n][256], k/v: kv[512][n]
//   stats[row] = (max_n k, 1/sum exp(k-max))
//   sim = P @ V^T (MFMA over n-chunks, partials summed)
//   M_b[o][32h+d] = sum_e out_w[o][32h+e]*sim[h,d,e]
//   out[b][o][n] = M . qT + out_b + x  (residual+store in native dtype)
//
// ws: xw 64Mi | wconv 1Mi | flag/gstats/beta/stats | pass scratch nb*64Mi
//     pass scratch: qT nb*16Mi | kv nb*32Mi | xt nb*16Mi
//     aliases: gn_part in kv (pre-GEMM1), M in kv (post-sim),
//              partials/sim in xt (post-GEMM1).

typedef __bf16 bf16x8 __attribute__((ext_vector_type(8)));
typedef float f32x4 __attribute__((ext_vector_type(4)));

union U16 { uint4 u; unsigned short s[8]; bf16x8 v; };

__device__ __forceinline__ float bf2f(unsigned short h) {
    unsigned int u = ((unsigned int)h) << 16;
    return __builtin_bit_cast(float, u);
}
__device__ __forceinline__ unsigned short f2bf(float f) {
    unsigned int u = __builtin_bit_cast(unsigned int, f);
    u = (u + 0x7fffu + ((u >> 16) & 1u)) >> 16;   // RNE
    return (unsigned short)u;
}
__device__ __forceinline__ unsigned int pack2(unsigned short a, unsigned short b) {
    return (unsigned int)a | ((unsigned int)b << 16);
}

// ------------------------------------------------------------- dtype probe
// If x is bf16, the LOW u16 of each u32 is a bf16 sample of N(0,1): its
// exponent field lies in [100,141] essentially always. If x is fp32, the low
// u16 is mantissa bits (uniform): ~16% hit that range. Ballot over 64 probes.
__global__ __launch_bounds__(64) void k_detect(const unsigned int* __restrict__ xr,
                                               int* __restrict__ flag) {
    unsigned int u = xr[threadIdx.x * 997];
    int e = (u >> 7) & 0xFF;
    bool ok = (e >= 100) && (e <= 141);
    unsigned long long m = __ballot(ok);
    if (threadIdx.x == 0) *flag = (__popcll(m) < 32) ? 1 : 0;   // 1 = fp32
}

// --------------------------------------------------- weight convert / copy
// wdst: qkvw[196608] | outw[65536] | gnw[256] | gnb[256] | outb[256]
__global__ __launch_bounds__(256) void k_cvt_w(const void* __restrict__ qkvw,
                                               const void* __restrict__ outw,
                                               const void* __restrict__ gnw,
                                               const void* __restrict__ gnb,
                                               const void* __restrict__ outb,
                                               const int* __restrict__ flagp,
                                               unsigned short* __restrict__ wdst) {
    int idx = blockIdx.x * 256 + threadIdx.x;
    if (idx >= 262912) return;
    const void* src; int off;
    if      (idx < 196608) { src = qkvw; off = idx; }
    else if (idx < 262144) { src = outw; off = idx - 196608; }
    else if (idx < 262400) { src = gnw;  off = idx - 262144; }
    else if (idx < 262656) { src = gnb;  off = idx - 262400; }
    else                   { src = outb; off = idx - 262656; }
    int f = *flagp;
    wdst[idx] = f ? f2bf(((const float*)src)[off])
                  : ((const unsigned short*)src)[off];
}

// ------------------------------------------------------- x convert / copy
__global__ __launch_bounds__(256) void k_cvt_x(const void* __restrict__ xr,
                                               const int* __restrict__ flagp,
                                               unsigned short* __restrict__ xw) {
    int f = *flagp;
    size_t base = ((size_t)blockIdx.x * 256 + threadIdx.x) * 8;
    if (f) {
        const float* xf = (const float*)xr;
        float4 a = *(const float4*)(xf + base);
        float4 c = *(const float4*)(xf + base + 4);
        U16 o;
        o.s[0] = f2bf(a.x); o.s[1] = f2bf(a.y); o.s[2] = f2bf(a.z); o.s[3] = f2bf(a.w);
        o.s[4] = f2bf(c.x); o.s[5] = f2bf(c.y); o.s[6] = f2bf(c.z); o.s[7] = f2bf(c.w);
        *(uint4*)(xw + base) = o.u;
    } else {
        *(uint4*)(xw + base) = *(const uint4*)((const unsigned short*)xr + base);
    }
}

// ---------------------------------------------------------------- GN stats
__global__ __launch_bounds__(256) void k_gnsum(const unsigned short* __restrict__ x,
                                               float2* __restrict__ gn_part) {
    int t = threadIdx.x, bid = blockIdx.x;
    int grp = bid >> 7, chunk = bid & 127;
    const unsigned short* p = x + (size_t)grp * 2097152 + (size_t)chunk * 16384;
    float s = 0.f, q = 0.f;
    for (int i = 0; i < 8; i++) {
        U16 u; u.u = *(const uint4*)(p + i * 2048 + t * 8);
#pragma unroll
        for (int j = 0; j < 8; j++) { float f = bf2f(u.s[j]); s += f; q += f * f; }
    }
#pragma unroll
    for (int off = 32; off > 0; off >>= 1) { s += __shfl_xor(s, off); q += __shfl_xor(q, off); }
    __shared__ float rs[4], rq[4];
    int wave = t >> 6;
    if ((t & 63) == 0) { rs[wave] = s; rq[wave] = q; }
    __syncthreads();
    if (t == 0) gn_part[bid] = make_float2(rs[0] + rs[1] + rs[2] + rs[3],
                                           rq[0] + rq[1] + rq[2] + rq[3]);
}

__global__ __launch_bounds__(128) void k_gnfinal(const float2* __restrict__ gn_part,
                                                 float2* __restrict__ gstats) {
    int bg = blockIdx.x, t = threadIdx.x;
    float2 v = gn_part[bg * 128 + t];
    float s = v.x, q = v.y;
#pragma unroll
    for (int off = 32; off > 0; off >>= 1) { s += __shfl_xor(s, off); q += __shfl_xor(q, off); }
    __shared__ float rs[2], rq[2];
    if ((t & 63) == 0) { rs[t >> 6] = s; rq[t >> 6] = q; }
    __syncthreads();
    if (t == 0) {
        const float inv = 1.0f / 2097152.0f;
        float S = rs[0] + rs[1], Q = rq[0] + rq[1];
        float mean = S * inv;
        float var = Q * inv - mean * mean;
        gstats[bg] = make_float2(mean, rsqrtf(var + 1e-5f));
    }
}

// ---------------------------------------------------------------- beta_b[o]
__global__ __launch_bounds__(64) void k_beta(const unsigned short* __restrict__ wq,
                                             const unsigned short* __restrict__ wgnw,
                                             const unsigned short* __restrict__ wgnb,
                                             const float2* __restrict__ gstats,
                                             float* __restrict__ beta) {
    int bid = blockIdx.x;
    int b = bid / 768, o = bid % 768;
    int t = threadIdx.x, c = t * 4;
    float2 ms = gstats[b * 4 + (c >> 6)];
    uint2 qw = *(const uint2*)(wq + o * 256 + c);
    uint2 gw = *(const uint2*)(wgnw + c);
    uint2 gb = *(const uint2*)(wgnb + c);
    unsigned short qs[4] = {(unsigned short)(qw.x & 0xffff), (unsigned short)(qw.x >> 16),
                            (unsigned short)(qw.y & 0xffff), (unsigned short)(qw.y >> 16)};
    unsigned short wsx[4] = {(unsigned short)(gw.x & 0xffff), (unsigned short)(gw.x >> 16),
                             (unsigned short)(gw.y & 0xffff), (unsigned short)(gw.y >> 16)};
    unsigned short bs[4] = {(unsigned short)(gb.x & 0xffff), (unsigned short)(gb.x >> 16),
                            (unsigned short)(gb.y & 0xffff), (unsigned short)(gb.y >> 16)};
    float bacc = 0.f;
#pragma unroll
    for (int j = 0; j < 4; j++)
        bacc += bf2f(qs[j]) * (bf2f(bs[j]) - ms.x * ms.y * bf2f(wsx[j]));
#pragma unroll
    for (int off = 32; off > 0; off >>= 1) bacc += __shfl_xor(bacc, off);
    if (t == 0) beta[b * 768 + o] = bacc;
}

// ------------------------------------------------- transpose + fold GN scale
__global__ __launch_bounds__(256) void k_transpose(const unsigned short* __restrict__ x,
                                                   const unsigned short* __restrict__ wgnw,
                                                   const float2* __restrict__ gstats,
                                                   unsigned short* __restrict__ xt) {
    int tid = threadIdx.x, bid = blockIdx.x;
    int b = bid >> 11, r2 = bid & 2047, cblk = r2 >> 9, nblk = r2 & 511;
    float rstd = gstats[b * 4 + cblk].y;
    __shared__ __align__(16) unsigned short T[64 * 80];
    unsigned short tmp[2][8];
#pragma unroll
    for (int i = 0; i < 2; i++) {
        int crow = (tid >> 3) + 32 * i, nch = tid & 7;
        int c = cblk * 64 + crow;
        float sc = bf2f(wgnw[c]) * rstd;
        U16 u; u.u = *(const uint4*)(x + ((size_t)(b * 256 + c)) * 32768 + (size_t)nblk * 64 + nch * 8);
#pragma unroll
        for (int j = 0; j < 8; j++) tmp[i][j] = f2bf(bf2f(u.s[j]) * sc);
    }
#pragma unroll
    for (int i = 0; i < 2; i++) {
        int crow = (tid >> 3) + 32 * i, nch = tid & 7;
#pragma unroll
        for (int jj = 0; jj < 8; jj++) {
            int j = (jj + tid) & 7;
            T[(nch * 8 + j) * 80 + crow] = tmp[i][j];
        }
    }
    __syncthreads();
#pragma unroll
    for (int i = 0; i < 2; i++) {
        int nrow = (tid >> 3) + 32 * i, cch = tid & 7;
        uint4 v = *(const uint4*)&T[nrow * 80 + cch * 8];
        *(uint4*)(xt + ((size_t)b * 32768 + (size_t)nblk * 64 + nrow) * 256 + cblk * 64 + cch * 8) = v;
    }
}

// ---------------------------------------------------------------- GEMM core
__device__ __forceinline__ void stage128x64(const unsigned short* __restrict__ g,
                                            unsigned short* __restrict__ lds, int tid) {
    int wave = tid >> 6;
    int lane = tid & 63;
    const unsigned short* gl = g + (size_t)(lane >> 3) * 256 + (lane & 7) * 8;
    uint4 v[4];
#pragma unroll
    for (int i = 0; i < 4; i++)
        v[i] = *(const uint4*)(gl + (size_t)(wave * 32 + i * 8) * 256);
#pragma unroll
    for (int i = 0; i < 4; i++) {
        int row = wave * 32 + i * 8 + (lane >> 3);
        *(uint4*)&lds[row * 64 + (lane & 7) * 8] = v[i];
    }
}

__device__ __forceinline__ void gemm_core(const unsigned short* __restrict__ A,
                                          const unsigned short* __restrict__ Bsrc,
                                          unsigned short* ldsA, unsigned short* ldsB,
                                          int tid, f32x4 (&acc)[4][4]) {
    int lane = tid & 63, l15 = lane & 15, quad = lane >> 4;
    int wave = tid >> 6, wm = wave & 1, wn = wave >> 1;
    for (int kt = 0; kt < 4; kt++) {
        stage128x64(A + kt * 64, ldsA, tid);
        stage128x64(Bsrc + kt * 64, ldsB, tid);
        __syncthreads();
#pragma unroll
        for (int ks = 0; ks < 2; ks++) {
            bf16x8 af[4], bv[4];
#pragma unroll
            for (int mi = 0; mi < 4; mi++)
                af[mi] = *(const bf16x8*)&ldsA[(wm * 64 + mi * 16 + l15) * 64 + ks * 32 + quad * 8];
#pragma unroll
            for (int ni = 0; ni < 4; ni++)
                bv[ni] = *(const bf16x8*)&ldsB[(wn * 64 + ni * 16 + l15) * 64 + ks * 32 + quad * 8];
#pragma unroll
            for (int mi = 0; mi < 4; mi++)
#pragma unroll
                for (int ni = 0; ni < 4; ni++)
                    acc[mi][ni] = __builtin_amdgcn_mfma_f32_16x16x32_bf16(af[mi], bv[ni], acc[mi][ni], 0, 0, 0);
        }
        __syncthreads();
    }
}

// GEMM1
__global__ __launch_bounds__(256) void k_gemm1(const unsigned short* __restrict__ wq,
                                               const unsigned short* __restrict__ xt,
                                               const float* __restrict__ beta,
                                               unsigned short* __restrict__ qT,
                                               unsigned short* __restrict__ kv) {
    __shared__ __align__(16) unsigned short ldsA[128 * 64];
    __shared__ __align__(16) unsigned short ldsB[128 * 64];
    int tid = threadIdx.x, bid = blockIdx.x;
    int b = bid / 1536, r = bid % 1536, mblk = r >> 8, nblk = r & 255;
    int o0 = mblk * 128;
    size_t n0 = (size_t)nblk * 128;
    const unsigned short* A = wq + (size_t)o0 * 256;
    const unsigned short* Bx = xt + ((size_t)b * 32768 + n0) * 256;
    f32x4 acc[4][4] = {};
    gemm_core(A, Bx, ldsA, ldsB, tid, acc);

    int lane = tid & 63, l15 = lane & 15, quad = lane >> 4;
    int wave = tid >> 6, wm = wave & 1, wn = wave >> 1;
    bool isQ = (mblk < 2);
#pragma unroll
    for (int mi = 0; mi < 4; mi++) {
        int o = o0 + wm * 64 + mi * 16 + quad * 4;
        float4 be = *(const float4*)(beta + b * 768 + o);
#pragma unroll
        for (int ni = 0; ni < 4; ni++) {
            size_t n = n0 + wn * 64 + ni * 16 + l15;
            f32x4 v = acc[mi][ni];
            unsigned short h0 = f2bf(v[0] + be.x), h1 = f2bf(v[1] + be.y);
            unsigned short h2 = f2bf(v[2] + be.z), h3 = f2bf(v[3] + be.w);
            if (isQ) {
                uint2 pv; pv.x = pack2(h0, h1); pv.y = pack2(h2, h3);
                *(uint2*)(qT + ((size_t)b * 32768 + n) * 256 + o) = pv;
            } else {
                int kvi = o - 256;
                unsigned short* bp = kv + ((size_t)b * 512 + kvi) * 32768 + n;
                bp[0] = h0; bp[32768] = h1; bp[65536] = h2; bp[98304] = h3;
            }
        }
    }
}

// ------------------------------------------------- softmax row stats
__global__ __launch_bounds__(256) void k_stats(const unsigned short* __restrict__ kv,
                                               float2* __restrict__ stats) {
    int row = blockIdx.x, t = threadIdx.x;
    const unsigned short* p = kv + ((size_t)(row >> 8) * 512 + (row & 255)) * 32768;
    float m = -3.0e38f;
    for (int i = 0; i < 16; i++) {
        U16 u; u.u = *(const uint4*)(p + i * 2048 + t * 8);
#pragma unroll
        for (int j = 0; j < 8; j++) m = fmaxf(m, bf2f(u.s[j]));
    }
#pragma unroll
    for (int off = 32; off > 0; off >>= 1) m = fmaxf(m, __shfl_xor(m, off));
    __shared__ float rm[4], rs[4];
    int wave = t >> 6;
    if ((t & 63) == 0) rm[wave] = m;
    __syncthreads();
    m = fmaxf(fmaxf(rm[0], rm[1]), fmaxf(rm[2], rm[3]));
    float s = 0.f;
    for (int i = 0; i < 16; i++) {
        U16 u; u.u = *(const uint4*)(p + i * 2048 + t * 8);
#pragma unroll
        for (int j = 0; j < 8; j++) s += __expf(bf2f(u.s[j]) - m);
    }
#pragma unroll
    for (int off = 32; off > 0; off >>= 1) s += __shfl_xor(s, off);
    if ((t & 63) == 0) rs[wave] = s;
    __syncthreads();
    if (t == 0) stats[row] = make_float2(m, 1.0f / (rs[0] + rs[1] + rs[2] + rs[3]));
}

// ----------------------------- sim partials
__global__ __launch_bounds__(64) void k_sim(const unsigned short* __restrict__ kv,
                                            const float2* __restrict__ stats,
                                            float* __restrict__ partials) {
    int bid = blockIdx.x;
    int bh = bid >> 6, chunk = bid & 63;
    int b = bh >> 3, h = bh & 7;
    int lane = threadIdx.x, l15 = lane & 15, quad = lane >> 4;
    size_t n0 = (size_t)chunk * 512 + quad * 8;
    float mrow[2], isr[2];
#pragma unroll
    for (int mi = 0; mi < 2; mi++) {
        float2 st = stats[b * 256 + h * 32 + mi * 16 + l15];
        mrow[mi] = st.x; isr[mi] = st.y;
    }
    const unsigned short* kb = kv + ((size_t)b * 512 + h * 32) * 32768;
    const unsigned short* vb = kv + ((size_t)b * 512 + 256 + h * 32) * 32768;
    f32x4 acc[2][2] = {};
    for (int t = 0; t < 16; t++) {
        size_t n = n0 + t * 32;
        bf16x8 af[2], bv[2];
#pragma unroll
        for (int mi = 0; mi < 2; mi++) {
            U16 u; u.u = *(const uint4*)(kb + (size_t)(mi * 16 + l15) * 32768 + n);
            U16 pv;
#pragma unroll
            for (int j = 0; j < 8; j++) pv.s[j] = f2bf(__expf(bf2f(u.s[j]) - mrow[mi]) * isr[mi]);
            af[mi] = pv.v;
        }
#pragma unroll
        for (int ni = 0; ni < 2; ni++) {
            U16 u; u.u = *(const uint4*)(vb + (size_t)(ni * 16 + l15) * 32768 + n);
            bv[ni] = u.v;
        }
#pragma unroll
        for (int mi = 0; mi < 2; mi++)
#pragma unroll
            for (int ni = 0; ni < 2; ni++)
                acc[mi][ni] = __builtin_amdgcn_mfma_f32_16x16x32_bf16(af[mi], bv[ni], acc[mi][ni], 0, 0, 0);
    }
    float* po = partials + (size_t)(bh * 64 + chunk) * 1024;
#pragma unroll
    for (int mi = 0; mi < 2; mi++)
#pragma unroll
        for (int ni = 0; ni < 2; ni++)
#pragma unroll
            for (int rr = 0; rr < 4; rr++)
                po[(mi * 16 + quad * 4 + rr) * 32 + ni * 16 + l15] = acc[mi][ni][rr];
}

__global__ __launch_bounds__(256) void k_combine(const float* __restrict__ partials,
                                                 float* __restrict__ sim) {
    int bh = blockIdx.x, tid = threadIdx.x;
#pragma unroll
    for (int i = 0; i < 4; i++) {
        float a = 0.f;
        const float* p = partials + (size_t)bh * 65536 + tid + i * 256;
        for (int c = 0; c < 64; c++) a += p[(size_t)c * 1024];
        sim[bh * 1024 + tid + i * 256] = a;
    }
}

__global__ __launch_bounds__(256) void k_buildM(const unsigned short* __restrict__ wo,
                                                const float* __restrict__ sim,
                                                unsigned short* __restrict__ M) {
    int bid = blockIdx.x, tid = threadIdx.x;
    int b = bid >> 8, o = bid & 255;
    __shared__ float lw[256];
    __shared__ float ls[8192];
    lw[tid] = bf2f(wo[o * 256 + tid]);
#pragma unroll
    for (int i = 0; i < 32; i++) ls[tid + i * 256] = sim[(size_t)b * 8192 + tid + i * 256];
    __syncthreads();
    int h = tid >> 5, d = tid & 31;
    float a = 0.f;
#pragma unroll
    for (int e = 0; e < 32; e++) {
        int ee = (e + d) & 31;
        a += lw[h * 32 + ee] * ls[h * 1024 + d * 32 + ee];
    }
    M[((size_t)b * 256 + o) * 256 + tid] = f2bf(a);
}

// GEMM2: out = M . qT + out_b + x   (residual + store in native dtype)
__global__ __launch_bounds__(256) void k_gemm2(const unsigned short* __restrict__ qT,
                                               const unsigned short* __restrict__ M,
                                               const unsigned short* __restrict__ wob,
                                               const void* __restrict__ xr,
                                               const int* __restrict__ flagp,
                                               void* __restrict__ outv,
                                               int b0) {
    __shared__ __align__(16) unsigned short ldsA[128 * 64];
    __shared__ __align__(16) unsigned short ldsB[128 * 64];
    int tid = threadIdx.x, bid = blockIdx.x;
    int b = bid >> 9, r = bid & 511, oblk = r >> 8, mblk = r & 255;
    size_t n0 = (size_t)mblk * 128;
    int o0 = oblk * 128;
    const unsigned short* A = qT + ((size_t)b * 32768 + n0) * 256;
    const unsigned short* Bm = M + ((size_t)b * 256 + o0) * 256;
    f32x4 acc[4][4] = {};
    gemm_core(A, Bm, ldsA, ldsB, tid, acc);

    int f = *flagp;
    int gb = b0 + b;
    int lane = tid & 63, l15 = lane & 15, quad = lane >> 4;
    int wave = tid >> 6, wm = wave & 1, wn = wave >> 1;
#pragma unroll
    for (int mi = 0; mi < 4; mi++) {
        size_t n = n0 + wm * 64 + mi * 16 + quad * 4;
#pragma unroll
        for (int ni = 0; ni < 4; ni++) {
            int o = o0 + wn * 64 + ni * 16 + l15;
            float bias = bf2f(wob[o]);
            size_t base = ((size_t)gb * 256 + o) * 32768 + n;
            f32x4 v = acc[mi][ni];
            if (f) {
                float4 xv = *(const float4*)((const float*)xr + base);
                float4 ov = make_float4(v[0] + bias + xv.x, v[1] + bias + xv.y,
                                        v[2] + bias + xv.z, v[3] + bias + xv.w);
                *(float4*)((float*)outv + base) = ov;
            } else {
                uint2 xr2 = *(const uint2*)((const unsigned short*)xr + base);
                unsigned short xs[4] = {(unsigned short)(xr2.x & 0xffff), (unsigned short)(xr2.x >> 16),
                                        (unsigned short)(xr2.y & 0xffff), (unsigned short)(xr2.y >> 16)};
                uint2 pv;
                pv.x = pack2(f2bf(v[0] + bias + bf2f(xs[0])), f2bf(v[1] + bias + bf2f(xs[1])));
                pv.y = pack2(f2bf(v[2] + bias + bf2f(xs[2])), f2bf(v[3] + bias + bf2f(xs[3])));
                *(uint2*)((unsigned short*)outv + base) = pv;
            }
        }
    }
}

extern "C" void kernel_launch(void* const* d_in, const int* in_sizes, int n_in,
                              void* d_out, int out_size, void* d_ws, size_t ws_size,
                              hipStream_t stream) {
    const void* x    = d_in[0];
    const void* gnw  = d_in[1];
    const void* gnb  = d_in[2];
    const void* qkvw = d_in[3];
    const void* outw = d_in[4];
    const void* outb = d_in[5];
    char* ws = (char*)d_ws;

    // Fixed region
    unsigned short* xw    = (unsigned short*)(ws);                    // 64 MiB
    unsigned short* wdst  = (unsigned short*)(ws + 67108864);         // ~0.51 MiB
    int*            flag  = (int*)(ws + 68157440);
    float2*         gstats= (float2*)(ws + 68157456);                 // <=128 B
    float*          beta  = (float*)(ws + 68158464);                  // <=12 KiB
    float2*         stats = (float2*)(ws + 68174848);                 // <=8 KiB
    const size_t passbase = 69206016;                                 // 66 MiB

    const unsigned short* wq   = wdst;
    const unsigned short* wo   = wdst + 196608;
    const unsigned short* wgnw = wdst + 262144;
    const unsigned short* wgnb = wdst + 262400;
    const unsigned short* wob  = wdst + 262656;

    int nb;
    if      (ws_size >= passbase + 4ull * 67108864) nb = 4;
    else if (ws_size >= passbase + 2ull * 67108864) nb = 2;
    else                                            nb = 1;

    size_t qT_off = passbase;
    size_t kv_off = passbase + (size_t)nb * 16777216;
    size_t xt_off = kv_off + (size_t)nb * 33554432;

    unsigned short* qT = (unsigned short*)(ws + qT_off);
    unsigned short* kv = (unsigned short*)(ws + kv_off);
    unsigned short* xt = (unsigned short*)(ws + xt_off);
    float2* gn_part    = (float2*)(ws + kv_off);                       // pre-GEMM1
    unsigned short* M  = (unsigned short*)(ws + kv_off);               // post-sim
    float* partials    = (float*)(ws + xt_off);                        // post-GEMM1
    float* sim         = (float*)(ws + xt_off + (size_t)nb * 2097152); // post-GEMM1

    k_detect<<<dim3(1), dim3(64), 0, stream>>>((const unsigned int*)x, flag);
    k_cvt_w<<<dim3(1027), dim3(256), 0, stream>>>(qkvw, outw, gnw, gnb, outb, flag, wdst);
    k_cvt_x<<<dim3(16384), dim3(256), 0, stream>>>(x, flag, xw);

    for (int pass = 0; pass < 4; pass += nb) {
        const unsigned short* xp = xw + (size_t)pass * 8388608;
        k_gnsum    <<<dim3(512 * nb),  dim3(256), 0, stream>>>(xp, gn_part);
        k_gnfinal  <<<dim3(4 * nb),    dim3(128), 0, stream>>>(gn_part, gstats);
        k_beta     <<<dim3(768 * nb),  dim3(64),  0, stream>>>(wq, wgnw, wgnb, gstats, beta);
        k_transpose<<<dim3(2048 * nb), dim3(256), 0, stream>>>(xp, wgnw, gstats, xt);
        k_gemm1    <<<dim3(1536 * nb), dim3(256), 0, stream>>>(wq, xt, beta, qT, kv);
        k_stats    <<<dim3(256 * nb),  dim3(256), 0, stream>>>(kv, stats);
        k_sim      <<<dim3(512 * nb),  dim3(64),  0, stream>>>(kv, stats, partials);
        k_combine  <<<dim3(8 * nb),    dim3(256), 0, stream>>>(partials, sim);
        k_buildM   <<<dim3(256 * nb),  dim3(256), 0, stream>>>(wo, sim, M);
        k_gemm2    <<<dim3(512 * nb),  dim3(256), 0, stream>>>(qT, M, wob, x, flag, d_out, pass);
    }
}